// Round 13
// baseline (452.901 us; speedup 1.0000x reference)
//
#include <hip/hip_runtime.h>
#include <hip/hip_bf16.h>

constexpr int NPT    = 50000;
constexpr int NN     = 100000;
constexpr int NE     = 1000000;
constexpr int HID    = 128;
constexpr int OUTF   = 64;
constexpr int INF    = 256;
constexpr int NREL   = 5;
constexpr int NSEG   = NN * NREL;
constexpr int NEB    = (NE + 255) / 256;   // 3907 edge blocks

typedef __attribute__((ext_vector_type(8))) short short8v;
typedef __attribute__((ext_vector_type(4))) float f32x4;

__device__ __forceinline__ ushort f2bf(float x) {
    uint u = __builtin_bit_cast(uint, x);
    uint r = (u + 0x7FFFu + ((u >> 16) & 1u)) >> 16;
    return (ushort)r;
}
__device__ __forceinline__ float bfhi(uint raw) {
    return __builtin_bit_cast(float, raw & 0xFFFF0000u);
}
__device__ __forceinline__ float bflo(uint raw) {
    return __builtin_bit_cast(float, raw << 16);
}

// ---------------------------------------------------------------------------
// fused prep: zero cnt/statscr/recs-pad + build all weight stacks in ONE launch
__device__ __forceinline__ void build_wbT_body(const float* __restrict__ comp,
                                               const float* __restrict__ basis,
                                               const float* __restrict__ root,
                                               ushort* __restrict__ wbT,
                                               int fout, int passOff, int idx) {
    int col = idx >> 7, k = idx & 127;
    float v;
    if (col < 320) {
        int r = col >> 6, f = (col & 63) + passOff;
        v = 0.f;
#pragma unroll
        for (int b = 0; b < 8; b++)
            v += comp[r * 8 + b] * basis[(b * 128 + k) * fout + f];
    } else {
        v = root[k * fout + (col - 320) + passOff];
    }
    wbT[col * 128 + k] = f2bf(v);
}

__global__ void prep_kernel(const float* __restrict__ comp0, const float* __restrict__ basis0,
                            const float* __restrict__ root0,
                            const float* __restrict__ comp1, const float* __restrict__ basis1,
                            const float* __restrict__ root1,
                            const float* __restrict__ paw, const float* __restrict__ ppw,
                            ushort* __restrict__ wbT0a, ushort* __restrict__ wbT0b,
                            ushort* __restrict__ wbT1,
                            ushort* __restrict__ wpa, ushort* __restrict__ wpp,
                            int* __restrict__ cnt, float* __restrict__ statscr,
                            int* __restrict__ recs_pad) {
    const int b = blockIdx.x, t = threadIdx.x;
    if (b < 1954) {                       // zero cnt[NSEG]
        int i = b * 256 + t;
        if (i < NSEG) cnt[i] = 0;
    } else if (b < 1979) {                // zero statscr[6400]
        statscr[(b - 1954) * 256 + t] = 0.f;
    } else if (b == 1979) {               // zero recs pad (64 int2)
        if (t < 128) recs_pad[t] = 0;
    } else if (b < 2172) {
        build_wbT_body(comp0, basis0, root0, wbT0a, HID, 0, (b - 1980) * 256 + t);
    } else if (b < 2364) {
        build_wbT_body(comp0, basis0, root0, wbT0b, HID, 64, (b - 2172) * 256 + t);
    } else if (b < 2556) {
        build_wbT_body(comp1, basis1, root1, wbT1, OUTF, 0, (b - 2364) * 256 + t);
    } else if (b < 2684) {                // wpa: w[256][128] -> wT[128][256]
        int i = (b - 2556) * 256 + t;
        wpa[(size_t)(i & 127) * 256 + (i >> 7)] = f2bf(paw[i]);
    } else {
        int i = (b - 2684) * 256 + t;
        wpp[(size_t)(i & 127) * 256 + (i >> 7)] = f2bf(ppw[i]);
    }
}

// ---------------------------------------------------------------------------
// proj + hist, role-INTERLEAVED so both kinds are co-resident from t=0:
//   gid%4==0 -> proj ordinal gid/4 (0..1249); else -> hist ordinal gid-gid/4-1.
__launch_bounds__(256)
__global__ void proj_hist(const float* __restrict__ xa, const float* __restrict__ xp,
                          const ushort* __restrict__ wTa, const ushort* __restrict__ wTp,
                          const float* __restrict__ ba, const float* __restrict__ bp,
                          ushort* __restrict__ x0b,
                          const int* __restrict__ ei, const int* __restrict__ et,
                          int* __restrict__ cnt, int* __restrict__ rank) {
    __shared__ ushort sx[16][264];
    __shared__ ushort so[16][132];
    const int tid = threadIdx.x;
    const int gid = blockIdx.x;
    if ((gid & 3) != 0) {                 // ---- hist part ----
        int ord = gid - (gid >> 2) - 1;
        if (ord >= NEB) return;
        int e = ord * 256 + tid;
        if (e < NE) {
            int seg = ei[NE + e] * NREL + et[e];
            rank[e] = atomicAdd(&cnt[seg], 1);
        }
        return;
    }
    const int pord = gid >> 2;
    if (pord >= 1250) return;
    // ---- proj part ----
    const bool author = pord < 625;
    const int tile0 = (pord - (author ? 0 : 625)) * 5;
    const float* x = author ? xa : xp;
    const ushort* wT = author ? wTa : wTp;
    const float* bias = author ? ba : bp;
    const int typeBase = author ? 0 : NPT;

    const int wave = tid >> 6, lane = tid & 63;
    const int row = lane & 15, g = lane >> 4;
    const int fcol = wave * 32 + row;

    const ushort* wp0 = wT + (size_t)fcol * 256 + g * 8;
    short8v bA[8], bB[8];
#pragma unroll
    for (int kk = 0; kk < 8; kk++) bA[kk] = *(const short8v*)&wp0[kk * 32];
#pragma unroll
    for (int kk = 0; kk < 8; kk++) bB[kk] = *(const short8v*)&wp0[16 * 256 + kk * 32];
    const float bv0 = bias[fcol], bv1 = bias[fcol + 16];

    const int sr = tid >> 4, part = tid & 15;
    const int fnode = tid >> 4, fb = (tid & 15) * 8;

    for (int t = 0; t < 5; t++) {
        const int nloc = (tile0 + t) * 16;
        {
            size_t rowoff = (size_t)(nloc + sr) * INF + part * 16;
#pragma unroll
            for (int ii = 0; ii < 4; ii++) {
                float4 v = *(const float4*)&x[rowoff + ii * 4];
                ushort4 h = {f2bf(v.x), f2bf(v.y), f2bf(v.z), f2bf(v.w)};
                *(ushort4*)&sx[sr][part * 16 + ii * 4] = h;
            }
        }
        __syncthreads();
        short8v a[8];
#pragma unroll
        for (int kk = 0; kk < 8; kk++) a[kk] = *(const short8v*)&sx[row][kk * 32 + g * 8];
        {
            f32x4 acc0 = {0.f, 0.f, 0.f, 0.f};
            f32x4 acc1 = {0.f, 0.f, 0.f, 0.f};
#pragma unroll
            for (int kk = 0; kk < 8; kk++) {
                acc0 = __builtin_amdgcn_mfma_f32_16x16x32_bf16(a[kk], bA[kk], acc0, 0, 0, 0);
                acc1 = __builtin_amdgcn_mfma_f32_16x16x32_bf16(a[kk], bB[kk], acc1, 0, 0, 0);
            }
#pragma unroll
            for (int q = 0; q < 4; q++) {
                so[g * 4 + q][fcol]      = f2bf(fmaxf(acc0[q] + bv0, 0.f));
                so[g * 4 + q][fcol + 16] = f2bf(fmaxf(acc1[q] + bv1, 0.f));
            }
        }
        __syncthreads();
        {
            ushort4 v0 = *(const ushort4*)&so[fnode][fb];
            ushort4 v1 = *(const ushort4*)&so[fnode][fb + 4];
            size_t gbase = (size_t)(typeBase + nloc + fnode) * 128 + fb;
            *(ushort4*)&x0b[gbase] = v0;
            *(ushort4*)&x0b[gbase + 4] = v1;
        }
    }
}

// ---------------------------------------------------------------------------
__global__ void scan1(const int* __restrict__ cnt, int* __restrict__ offs,
                      int* __restrict__ bsums, int n) {
    __shared__ int lds[256];
    const int t = threadIdx.x;
    const int base = blockIdx.x * 2048 + t * 8;
    int vals[8];
    int s = 0;
#pragma unroll
    for (int v = 0; v < 8; v++) {
        int idx = base + v;
        vals[v] = (idx < n) ? cnt[idx] : 0;
        s += vals[v];
    }
    lds[t] = s;
    __syncthreads();
    for (int off = 1; off < 256; off <<= 1) {
        int x = lds[t];
        int y = (t >= off) ? lds[t - off] : 0;
        __syncthreads();
        lds[t] = x + y;
        __syncthreads();
    }
    int run = (t > 0) ? lds[t - 1] : 0;
    if (t == 255) bsums[blockIdx.x] = lds[255];
#pragma unroll
    for (int v = 0; v < 8; v++) {
        int idx = base + v;
        if (idx < n) offs[idx] = run;
        run += vals[v];
    }
}

__global__ void scan2(const int* __restrict__ bsums, int* __restrict__ bsums2, int nb) {
    __shared__ int lds[256];
    const int t = threadIdx.x;
    lds[t] = (t < nb) ? bsums[t] : 0;
    __syncthreads();
    for (int off = 1; off < 256; off <<= 1) {
        int x = lds[t];
        int y = (t >= off) ? lds[t - off] : 0;
        __syncthreads();
        lds[t] = x + y;
        __syncthreads();
    }
    if (t < nb) bsums2[t] = (t > 0) ? lds[t - 1] : 0;
}

__global__ void scan3_desc(const int* __restrict__ offs, const int* __restrict__ bsums2,
                           const int* __restrict__ cnt, int2* __restrict__ desc, int n) {
    int i = blockIdx.x * blockDim.x + threadIdx.x;
    if (i < n) {
        int2 d = {offs[i] + bsums2[i >> 11], cnt[i]};
        desc[i] = d;
    }
}

// ---------------------------------------------------------------------------
// L0 dense GEMM + scatter, role-INTERLEAVED (gid%4==0 -> gemm, else scatter).
// Root contribution goes to bf16 seed0 (not f32 h).
__launch_bounds__(256)
__global__ void gemm0_scatter(const ushort* __restrict__ xin,
                              const ushort* __restrict__ wbT_a, const ushort* __restrict__ wbT_b,
                              ushort* __restrict__ ytab, ushort* __restrict__ seed0,
                              const int* __restrict__ ei, const int* __restrict__ et,
                              const int* __restrict__ rank,
                              const int2* __restrict__ desc, int2* __restrict__ recs) {
    __shared__ ushort sx[32][136];
    __shared__ ushort so[32][328];
    __shared__ float sroot[32][68];
    const int tid = threadIdx.x;
    const int gid = blockIdx.x;
    if ((gid & 3) != 0) {                 // ---- scatter part ----
        int ord = gid - (gid >> 2) - 1;
        if (ord >= NEB) return;
        int e = ord * 256 + tid;
        if (e < NE) {
            int src = ei[e];
            int dst = ei[NE + e];
            int r = et[e];
            int2 d = desc[dst * NREL + r];
            int c = d.y;
            float sc = 1.f / (float)((c > 1) ? c : 1);
            int2 rec = {r * NN + src, __builtin_bit_cast(int, sc)};
            recs[d.x + rank[e]] = rec;
        }
        return;
    }
    const int gord = gid >> 2;
    if (gord >= 1250) return;
    // ---- gemm0 part ----
    const bool first = gord < 625;
    const int tile0 = (first ? gord : gord - 625) * 5;
    const ushort* wbT = first ? wbT_a : wbT_b;
    const int outOff = first ? 0 : 64;
    const int wave = tid >> 6, lane = tid & 63;
    const int row = lane & 15, g = lane >> 4;
    const int wbase = wave * 96;

    const ushort* wp = wbT + (size_t)(wbase + row) * 128 + g * 8;
    short8v B[6][4];
#pragma unroll
    for (int t = 0; t < 6; t++)
#pragma unroll
        for (int kk = 0; kk < 4; kk++)
            B[t][kk] = *(const short8v*)&wp[t * 2048 + kk * 32];

    const int sr = tid >> 3, scl = (tid & 7) * 16;
    const int fnode = tid >> 3, fb = (tid & 7) * 8;

    for (int tt = 0; tt < 5; tt++) {
        const int n0 = (tile0 + tt) * 32;
        {
            const ushort* src = &xin[(size_t)(n0 + sr) * 128 + scl];
            *(short8v*)&sx[sr][scl] = *(const short8v*)&src[0];
            *(short8v*)&sx[sr][scl + 8] = *(const short8v*)&src[8];
        }
        __syncthreads();

        short8v a[2][4];
#pragma unroll
        for (int m = 0; m < 2; m++)
#pragma unroll
            for (int kk = 0; kk < 4; kk++)
                a[m][kk] = *(const short8v*)&sx[m * 16 + row][kk * 32 + g * 8];

#pragma unroll
        for (int t = 0; t < 6; t++) {
            f32x4 acc0 = {0.f, 0.f, 0.f, 0.f};
            f32x4 acc1 = {0.f, 0.f, 0.f, 0.f};
#pragma unroll
            for (int kk = 0; kk < 4; kk++) {
                acc0 = __builtin_amdgcn_mfma_f32_16x16x32_bf16(a[0][kk], B[t][kk], acc0, 0, 0, 0);
                acc1 = __builtin_amdgcn_mfma_f32_16x16x32_bf16(a[1][kk], B[t][kk], acc1, 0, 0, 0);
            }
            const int col = wbase + t * 16 + row;
            if (col < 320) {
#pragma unroll
                for (int q = 0; q < 4; q++) {
                    so[g * 4 + q][col] = f2bf(acc0[q]);
                    so[16 + g * 4 + q][col] = f2bf(acc1[q]);
                }
            } else {
                const int f = col - 320;
#pragma unroll
                for (int q = 0; q < 4; q++) {
                    sroot[g * 4 + q][f] = acc0[q];
                    sroot[16 + g * 4 + q][f] = acc1[q];
                }
            }
        }
        __syncthreads();

        {
#pragma unroll
            for (int r = 0; r < NREL; r++) {
                short8v v = *(const short8v*)&so[fnode][r * 64 + fb];
                *(short8v*)&ytab[(size_t)r * NN * 128 + (size_t)(n0 + fnode) * 128
                                 + outOff + fb] = v;
            }
            float4 r0 = *(const float4*)&sroot[fnode][fb];
            float4 r1 = *(const float4*)&sroot[fnode][fb + 4];
            ushort sb[8] = {f2bf(r0.x), f2bf(r0.y), f2bf(r0.z), f2bf(r0.w),
                            f2bf(r1.x), f2bf(r1.y), f2bf(r1.z), f2bf(r1.w)};
            *(short8v*)&seed0[(size_t)(n0 + fnode) * 128 + outOff + fb] =
                *(const short8v*)sb;
        }
    }
}

// ---------------------------------------------------------------------------
// L1 dense GEMM with FUSED PairNorm-0 on input (writes x_latent in place);
// root contribution goes to bf16 seed1.
__launch_bounds__(256)
__global__ void ytab_gemm1(float* __restrict__ h0x, const float* __restrict__ mu,
                           const ushort* __restrict__ wbT,
                           ushort* __restrict__ ytab, ushort* __restrict__ seed1) {
    __shared__ ushort sx[32][136];
    __shared__ ushort so[32][328];
    __shared__ float sroot[32][68];
    const int tid = threadIdx.x;
    const int tile0 = blockIdx.x * 5;
    const int wave = tid >> 6, lane = tid & 63;
    const int row = lane & 15, g = lane >> 4;
    const int wbase = wave * 96;

    const ushort* wp = wbT + (size_t)(wbase + row) * 128 + g * 8;
    short8v B[6][4];
#pragma unroll
    for (int t = 0; t < 6; t++)
#pragma unroll
        for (int kk = 0; kk < 4; kk++)
            B[t][kk] = *(const short8v*)&wp[t * 2048 + kk * 32];

    const int sr = tid >> 3, scl = (tid & 7) * 16;
    const int fnode = tid >> 3, fb = (tid & 7) * 8;

    float m[16];
#pragma unroll
    for (int i = 0; i < 16; i++) m[i] = mu[scl + i];
    const float s = mu[128];

    for (int tt = 0; tt < 5; tt++) {
        const int n0 = (tile0 + tt) * 32;
        {   // stage + normalize + write-back (in place)
            float* hp = &h0x[(size_t)(n0 + sr) * 128 + scl];
            float v[16];
#pragma unroll
            for (int i = 0; i < 4; i++) {
                float4 t4 = *(const float4*)&hp[i * 4];
                v[i * 4 + 0] = (t4.x - m[i * 4 + 0]) * s;
                v[i * 4 + 1] = (t4.y - m[i * 4 + 1]) * s;
                v[i * 4 + 2] = (t4.z - m[i * 4 + 2]) * s;
                v[i * 4 + 3] = (t4.w - m[i * 4 + 3]) * s;
            }
            ushort hb[16];
#pragma unroll
            for (int i = 0; i < 16; i++) hb[i] = f2bf(v[i]);
#pragma unroll
            for (int i = 0; i < 4; i++) {
                float4 t4 = {v[i * 4], v[i * 4 + 1], v[i * 4 + 2], v[i * 4 + 3]};
                *(float4*)&hp[i * 4] = t4;
            }
            *(short8v*)&sx[sr][scl] = *(const short8v*)&hb[0];
            *(short8v*)&sx[sr][scl + 8] = *(const short8v*)&hb[8];
        }
        __syncthreads();

        short8v a[2][4];
#pragma unroll
        for (int mi = 0; mi < 2; mi++)
#pragma unroll
            for (int kk = 0; kk < 4; kk++)
                a[mi][kk] = *(const short8v*)&sx[mi * 16 + row][kk * 32 + g * 8];

#pragma unroll
        for (int t = 0; t < 6; t++) {
            f32x4 acc0 = {0.f, 0.f, 0.f, 0.f};
            f32x4 acc1 = {0.f, 0.f, 0.f, 0.f};
#pragma unroll
            for (int kk = 0; kk < 4; kk++) {
                acc0 = __builtin_amdgcn_mfma_f32_16x16x32_bf16(a[0][kk], B[t][kk], acc0, 0, 0, 0);
                acc1 = __builtin_amdgcn_mfma_f32_16x16x32_bf16(a[1][kk], B[t][kk], acc1, 0, 0, 0);
            }
            const int col = wbase + t * 16 + row;
            if (col < 320) {
#pragma unroll
                for (int q = 0; q < 4; q++) {
                    so[g * 4 + q][col] = f2bf(acc0[q]);
                    so[16 + g * 4 + q][col] = f2bf(acc1[q]);
                }
            } else {
                const int f = col - 320;
#pragma unroll
                for (int q = 0; q < 4; q++) {
                    sroot[g * 4 + q][f] = acc0[q];
                    sroot[16 + g * 4 + q][f] = acc1[q];
                }
            }
        }
        __syncthreads();

        {
#pragma unroll
            for (int r = 0; r < NREL; r++) {
                short8v v = *(const short8v*)&so[fnode][r * 64 + fb];
                *(short8v*)&ytab[(size_t)r * NN * 64 + (size_t)(n0 + fnode) * 64 + fb] = v;
            }
            float4 r0 = *(const float4*)&sroot[fnode][fb];
            float4 r1 = *(const float4*)&sroot[fnode][fb + 4];
            ushort sb[8] = {f2bf(r0.x), f2bf(r0.y), f2bf(r0.z), f2bf(r0.w),
                            f2bf(r1.x), f2bf(r1.y), f2bf(r1.z), f2bf(r1.w)};
            *(short8v*)&seed1[(size_t)(n0 + fnode) * 64 + fb] = *(const short8v*)sb;
        }
    }
}

// ---------------------------------------------------------------------------
// Aggregation + FUSED PairNorm stats. Quarter-wave (16 lanes) per edge,
// wave-uniform trip count (shfl-safe). Seed read is bf16 (seed buffer);
// final h written f32.
template <int FW, bool RELU>
__launch_bounds__(256)
__global__ void agg_kernel(const ushort* __restrict__ ytab,
                           const ushort* __restrict__ seed,
                           const int2* __restrict__ recs,
                           const int2* __restrict__ desc,
                           float* __restrict__ hout,
                           float* __restrict__ csrep, float* __restrict__ ssrep) {
    constexpr int FPL = FW / 16;          // floats per lane (8 or 4)
    __shared__ float sred[4][16][FPL + 1];
    const int tid = threadIdx.x;
    const int wave = tid >> 6, lane = tid & 63;
    const int q = lane >> 4, fl = lane & 15;
    const int n0 = blockIdx.x * 16 + wave * 4;

    int start[4], total[4];
#pragma unroll
    for (int rep = 0; rep < 4; rep++) {
        const int s5 = (n0 + rep) * NREL;
        int2 d0 = desc[s5];
        int2 d4 = desc[s5 + 4];
        start[rep] = d0.x;
        total[rep] = d4.x + d4.y - d0.x;
    }
    float hpre[4][FPL];
#pragma unroll
    for (int rep = 0; rep < 4; rep++) {
        if (FW == 128) {
            uint4 sraw = *(const uint4*)&seed[(size_t)(n0 + rep) * FW + fl * 8];
            hpre[rep][0] = bflo(sraw.x); hpre[rep][1] = bfhi(sraw.x);
            hpre[rep][2] = bflo(sraw.y); hpre[rep][3] = bfhi(sraw.y);
            hpre[rep][4] = bflo(sraw.z); hpre[rep][5] = bfhi(sraw.z);
            hpre[rep][6] = bflo(sraw.w); hpre[rep][7] = bfhi(sraw.w);
        } else {
            uint2 sraw = *(const uint2*)&seed[(size_t)(n0 + rep) * FW + fl * 4];
            hpre[rep][0] = bflo(sraw.x); hpre[rep][1] = bfhi(sraw.x);
            hpre[rep][2] = bflo(sraw.y); hpre[rep][3] = bfhi(sraw.y);
        }
    }
    int2 rec[4];
#pragma unroll
    for (int rep = 0; rep < 4; rep++) rec[rep] = recs[start[rep] + lane];  // pad-safe

    float cs_loc[FPL];
#pragma unroll
    for (int k = 0; k < FPL; k++) cs_loc[k] = 0.f;
    float ss_loc = 0.f;

#pragma unroll
    for (int rep = 0; rep < 4; rep++) {
        float acc[FPL];
#pragma unroll
        for (int k = 0; k < FPL; k++) acc[k] = 0.f;
        const int lim = (total[rep] > 64) ? 64 : total[rep];   // wave-uniform
        const int iters = (lim + 3) >> 2;                      // wave-uniform
#pragma unroll 2
        for (int it = 0; it < iters; it++) {
            const int j4 = it * 4 + q;                         // <= 63 always
            int rwr = __shfl(rec[rep].x, j4);
            int scb = __shfl(rec[rep].y, j4);
            const bool ok = j4 < lim;
            const int rw = ok ? rwr : 0;
            const float sc = ok ? __builtin_bit_cast(float, scb) : 0.f;
            if (FW == 128) {
                uint4 raw = *(const uint4*)&ytab[(size_t)rw * FW + fl * 8];
                acc[0] += sc * bflo(raw.x); acc[1] += sc * bfhi(raw.x);
                acc[2] += sc * bflo(raw.y); acc[3] += sc * bfhi(raw.y);
                acc[4] += sc * bflo(raw.z); acc[5] += sc * bfhi(raw.z);
                acc[6] += sc * bflo(raw.w); acc[7] += sc * bfhi(raw.w);
            } else {
                uint2 raw = *(const uint2*)&ytab[(size_t)rw * FW + fl * 4];
                acc[0] += sc * bflo(raw.x); acc[1] += sc * bfhi(raw.x);
                acc[2] += sc * bflo(raw.y); acc[3] += sc * bfhi(raw.y);
            }
        }
        if (total[rep] > 64) {            // rare fallback (no shfl -> safe)
            for (int j = 64 + q; j < total[rep]; j += 4) {
                int2 r2 = recs[start[rep] + j];
                float sc = __builtin_bit_cast(float, r2.y);
                if (FW == 128) {
                    uint4 raw = *(const uint4*)&ytab[(size_t)r2.x * FW + fl * 8];
                    acc[0] += sc * bflo(raw.x); acc[1] += sc * bfhi(raw.x);
                    acc[2] += sc * bflo(raw.y); acc[3] += sc * bfhi(raw.y);
                    acc[4] += sc * bflo(raw.z); acc[5] += sc * bfhi(raw.z);
                    acc[6] += sc * bflo(raw.w); acc[7] += sc * bfhi(raw.w);
                } else {
                    uint2 raw = *(const uint2*)&ytab[(size_t)r2.x * FW + fl * 4];
                    acc[0] += sc * bflo(raw.x); acc[1] += sc * bfhi(raw.x);
                    acc[2] += sc * bflo(raw.y); acc[3] += sc * bfhi(raw.y);
                }
            }
        }
#pragma unroll
        for (int k = 0; k < FPL; k++) {
            acc[k] += __shfl_xor(acc[k], 32);
            acc[k] += __shfl_xor(acc[k], 16);
        }
        if (q == 0) {
            float o[FPL];
#pragma unroll
            for (int k = 0; k < FPL; k++) {
                o[k] = hpre[rep][k] + acc[k];
                if (RELU) o[k] = fmaxf(o[k], 0.f);
                cs_loc[k] += o[k];
                ss_loc += o[k] * o[k];
            }
            float* hp = &hout[(size_t)(n0 + rep) * FW + fl * FPL];
#pragma unroll
            for (int k = 0; k < FPL; k += 4)
                *(float4*)&hp[k] = *(float4*)&o[k];
        }
    }

    // block-level stats reduce -> replicated global accumulators
    if (q == 0) {
#pragma unroll
        for (int k = 0; k < FPL; k++) sred[wave][fl][k] = cs_loc[k];
        sred[wave][fl][FPL] = ss_loc;
    }
    __syncthreads();
    const int repl = blockIdx.x & 31;
    if (tid < FW) {
        int k = tid & (FPL - 1), f2 = tid / FPL;
        float sv = sred[0][f2][k] + sred[1][f2][k] + sred[2][f2][k] + sred[3][f2][k];
        atomicAdd(&csrep[repl * FW + f2 * FPL + k], sv);
    }
    if (tid < 16) {
        float ssv = sred[0][tid][FPL] + sred[1][tid][FPL]
                  + sred[2][tid][FPL] + sred[3][tid][FPL];
#pragma unroll
        for (int mof = 8; mof > 0; mof >>= 1) ssv += __shfl_xor(ssv, mof);
        if (tid == 0) atomicAdd(&ssrep[repl], ssv);
    }
}

// ---------------------------------------------------------------------------
template <int F>
__global__ void finalize_rep(const float* __restrict__ csrep,
                             const float* __restrict__ ssrep,
                             float* __restrict__ mu_inv) {
    __shared__ float sred[128];
    const int f = threadIdx.x;            // F threads
    float s = 0.f;
    for (int r = 0; r < 32; r++) s += csrep[r * F + f];
    float mu = s / (float)NN;
    mu_inv[f] = mu;
    sred[f] = mu * mu;
    __syncthreads();
    for (int h = F / 2; h > 0; h >>= 1) {
        if (f < h) sred[f] += sred[f + h];
        __syncthreads();
    }
    if (f == 0) {
        float ss = 0.f;
        for (int r = 0; r < 32; r++) ss += ssrep[r];
        float var = ss / (float)NN - sred[0];
        mu_inv[F] = rsqrtf(1e-5f + var);
    }
}

// final L1 normalize (in-place on d_out), float4-vectorized
template <int F>
__global__ void normalize_kernel(const float* __restrict__ x,
                                 const float* __restrict__ mu_inv,
                                 float* __restrict__ out, int total4) {
    int i = blockIdx.x * blockDim.x + threadIdx.x;
    if (i < total4) {
        int base = i * 4;
        int f = base & (F - 1);
        float4 v = *(const float4*)&x[base];
        float4 m = *(const float4*)&mu_inv[f];
        float s = mu_inv[F];
        float4 o = {(v.x - m.x) * s, (v.y - m.y) * s, (v.z - m.z) * s, (v.w - m.w) * s};
        *(float4*)&out[base] = o;
    }
}

// ---------------------------------------------------------------------------
extern "C" void kernel_launch(void* const* d_in, const int* in_sizes, int n_in,
                              void* d_out, int out_size, void* d_ws, size_t ws_size,
                              hipStream_t stream) {
    const float* xa    = (const float*)d_in[0];
    const float* xp    = (const float*)d_in[1];
    const int*   ei    = (const int*)d_in[2];
    const int*   et    = (const int*)d_in[3];
    const float* paw   = (const float*)d_in[4];
    const float* pab   = (const float*)d_in[5];
    const float* ppw   = (const float*)d_in[6];
    const float* ppb   = (const float*)d_in[7];
    const float* comp0 = (const float*)d_in[8];
    const float* basis0= (const float*)d_in[9];
    const float* root0 = (const float*)d_in[10];
    const float* comp1 = (const float*)d_in[11];
    const float* basis1= (const float*)d_in[12];
    const float* root1 = (const float*)d_in[13];
    float* out = (float*)d_out;

    char* ws = (char*)d_ws;
    size_t o = 0;
    auto alloc = [&](size_t b) { size_t p = o; o += (b + 255) & ~(size_t)255; return p; };
    ushort* x0b    = (ushort*)(ws + alloc((size_t)NN * HID * 2));        // 25.6 MB
    ushort* ytab   = (ushort*)(ws + alloc((size_t)NREL * NN * 128 * 2)); // 128 MB
    ushort* seed0  = (ushort*)(ws + alloc((size_t)NN * HID * 2));        // 25.6 MB
    ushort* seed1  = (ushort*)(ws + alloc((size_t)NN * OUTF * 2));       // 12.8 MB
    int2*   desc   = (int2*)(ws + alloc((size_t)NSEG * 8));              // 4 MB
    int2*   recs   = (int2*)(ws + alloc((size_t)(NE + 64) * 8));         // 8 MB
    int*    rank   = (int*)(ws + alloc((size_t)NE * 4));                 // 4 MB
    ushort* wbT0a  = (ushort*)(ws + alloc(384 * 128 * 2));
    ushort* wbT0b  = (ushort*)(ws + alloc(384 * 128 * 2));
    ushort* wbT1   = (ushort*)(ws + alloc(384 * 128 * 2));
    ushort* wpa    = (ushort*)(ws + alloc(128 * 256 * 2));
    ushort* wpp    = (ushort*)(ws + alloc(128 * 256 * 2));
    float*  statscr= (float*)(ws + alloc(6400 * 4));
    float*  mu0    = (float*)(ws + alloc(129 * 4));
    float*  mu1    = (float*)(ws + alloc(65 * 4));
    float* cs0rep = statscr;              // 32 x 128
    float* ss0rep = statscr + 4096;       // 32
    float* cs1rep = statscr + 4128;       // 32 x 64
    float* ss1rep = statscr + 6176;       // 32

    // index-build scratch aliased into ytab (cnt/offs/bsums dead after scan3_desc,
    // which completes before the first ytab write in gemm0_scatter)
    char* ybase = (char*)ytab;
    int* cnt    = (int*)(ybase);
    int* offs   = (int*)(ybase + (size_t)NSEG * 4);
    int* bsums  = (int*)(ybase + (size_t)NSEG * 8);
    int* bsums2 = (int*)(ybase + (size_t)NSEG * 8 + 4096);

    float* h0 = out + (size_t)NN * OUTF;   // [NN][128] f32 (x_latent slice)
    float* h1 = out;                       // [NN][64]  f32

    // prep (zeros + all weight builds), then proj FUSED+interleaved with hist
    prep_kernel<<<2812, 256, 0, stream>>>(comp0, basis0, root0, comp1, basis1, root1,
                                          paw, ppw, wbT0a, wbT0b, wbT1, wpa, wpp,
                                          cnt, statscr, (int*)(recs + NE));
    proj_hist<<<5210, 256, 0, stream>>>(xa, xp, wpa, wpp, pab, ppb,
                                        x0b, ei, et, cnt, rank);

    // segment index
    const int nb = (NSEG + 2047) / 2048;
    scan1<<<nb, 256, 0, stream>>>(cnt, offs, bsums, NSEG);
    scan2<<<1, 256, 0, stream>>>(bsums, bsums2, nb);
    scan3_desc<<<(NSEG + 255) / 256, 256, 0, stream>>>(offs, bsums2, cnt, desc, NSEG);

    // layer 0: GEMM (both halves) FUSED+interleaved with scatter, agg+stats, finalize
    gemm0_scatter<<<5210, 256, 0, stream>>>(x0b, wbT0a, wbT0b, ytab, seed0,
                                            ei, et, rank, desc, recs);
    agg_kernel<128, true><<<NN / 16, 256, 0, stream>>>(ytab, seed0, recs, desc, h0,
                                                       cs0rep, ss0rep);
    finalize_rep<128><<<1, 128, 0, stream>>>(cs0rep, ss0rep, mu0);

    // layer 1: GEMM with fused PairNorm-0 (writes x_latent in place), agg+stats
    ytab_gemm1<<<625, 256, 0, stream>>>(h0, mu0, wbT1, ytab, seed1);
    agg_kernel<64, false><<<NN / 16, 256, 0, stream>>>(ytab, seed1, recs, desc, h1,
                                                       cs1rep, ss1rep);
    finalize_rep<64><<<1, 64, 0, stream>>>(cs1rep, ss1rep, mu1);
    normalize_kernel<OUTF><<<(NN * OUTF / 4 + 255) / 256, 256, 0, stream>>>(h1, mu1, out,
                                                                            NN * OUTF / 4);
}

// Round 14
// 342.393 us; speedup vs baseline: 1.3228x; 1.3228x over previous
//
#include <hip/hip_runtime.h>
#include <hip/hip_bf16.h>

constexpr int NPT    = 50000;
constexpr int NN     = 100000;
constexpr int NE     = 1000000;
constexpr int HID    = 128;
constexpr int OUTF   = 64;
constexpr int INF    = 256;
constexpr int NREL   = 5;
constexpr int NSEG   = NN * NREL;
constexpr int NEB    = (NE + 255) / 256;   // 3907 edge blocks

typedef __attribute__((ext_vector_type(8))) short short8v;
typedef __attribute__((ext_vector_type(4))) float f32x4;

__device__ __forceinline__ ushort f2bf(float x) {
    uint u = __builtin_bit_cast(uint, x);
    uint r = (u + 0x7FFFu + ((u >> 16) & 1u)) >> 16;
    return (ushort)r;
}
__device__ __forceinline__ float bfhi(uint raw) {
    return __builtin_bit_cast(float, raw & 0xFFFF0000u);
}
__device__ __forceinline__ float bflo(uint raw) {
    return __builtin_bit_cast(float, raw << 16);
}

// ---------------------------------------------------------------------------
// fused prep: zero cnt/statscr/recs-pad + build all weight stacks in ONE launch
__device__ __forceinline__ void build_wbT_body(const float* __restrict__ comp,
                                               const float* __restrict__ basis,
                                               const float* __restrict__ root,
                                               ushort* __restrict__ wbT,
                                               int fout, int passOff, int idx) {
    int col = idx >> 7, k = idx & 127;
    float v;
    if (col < 320) {
        int r = col >> 6, f = (col & 63) + passOff;
        v = 0.f;
#pragma unroll
        for (int b = 0; b < 8; b++)
            v += comp[r * 8 + b] * basis[(b * 128 + k) * fout + f];
    } else {
        v = root[k * fout + (col - 320) + passOff];
    }
    wbT[col * 128 + k] = f2bf(v);
}

__global__ void prep_kernel(const float* __restrict__ comp0, const float* __restrict__ basis0,
                            const float* __restrict__ root0,
                            const float* __restrict__ comp1, const float* __restrict__ basis1,
                            const float* __restrict__ root1,
                            const float* __restrict__ paw, const float* __restrict__ ppw,
                            ushort* __restrict__ wbT0a, ushort* __restrict__ wbT0b,
                            ushort* __restrict__ wbT1,
                            ushort* __restrict__ wpa, ushort* __restrict__ wpp,
                            int* __restrict__ cnt, float* __restrict__ statscr,
                            int* __restrict__ recs_pad) {
    const int b = blockIdx.x, t = threadIdx.x;
    if (b < 1954) {                       // zero cnt[NSEG]
        int i = b * 256 + t;
        if (i < NSEG) cnt[i] = 0;
    } else if (b < 1979) {                // zero statscr[6400]
        statscr[(b - 1954) * 256 + t] = 0.f;
    } else if (b == 1979) {               // zero recs pad (64 int2)
        if (t < 128) recs_pad[t] = 0;
    } else if (b < 2172) {
        build_wbT_body(comp0, basis0, root0, wbT0a, HID, 0, (b - 1980) * 256 + t);
    } else if (b < 2364) {
        build_wbT_body(comp0, basis0, root0, wbT0b, HID, 64, (b - 2172) * 256 + t);
    } else if (b < 2556) {
        build_wbT_body(comp1, basis1, root1, wbT1, OUTF, 0, (b - 2364) * 256 + t);
    } else if (b < 2684) {                // wpa: w[256][128] -> wT[128][256]
        int i = (b - 2556) * 256 + t;
        wpa[(size_t)(i & 127) * 256 + (i >> 7)] = f2bf(paw[i]);
    } else {
        int i = (b - 2684) * 256 + t;
        wpp[(size_t)(i & 127) * 256 + (i >> 7)] = f2bf(ppw[i]);
    }
}

// ---------------------------------------------------------------------------
// proj (blocks 0..1249, B-stationary 5-tile loop) + hist (blocks 1250+),
// RANGE-SPLIT (temporal partitioning — R13's interleave regressed 2x).
__launch_bounds__(256)
__global__ void proj_hist(const float* __restrict__ xa, const float* __restrict__ xp,
                          const ushort* __restrict__ wTa, const ushort* __restrict__ wTp,
                          const float* __restrict__ ba, const float* __restrict__ bp,
                          ushort* __restrict__ x0b,
                          const int* __restrict__ ei, const int* __restrict__ et,
                          int* __restrict__ cnt, int* __restrict__ rank) {
    __shared__ ushort sx[16][264];
    __shared__ ushort so[16][132];
    const int tid = threadIdx.x;
    if (blockIdx.x >= 1250) {             // ---- hist part ----
        int e = (blockIdx.x - 1250) * 256 + tid;
        if (e < NE) {
            int seg = ei[NE + e] * NREL + et[e];
            rank[e] = atomicAdd(&cnt[seg], 1);
        }
        return;
    }
    // ---- proj part ----
    const bool author = blockIdx.x < 625;
    const int tile0 = (blockIdx.x - (author ? 0 : 625)) * 5;
    const float* x = author ? xa : xp;
    const ushort* wT = author ? wTa : wTp;
    const float* bias = author ? ba : bp;
    const int typeBase = author ? 0 : NPT;

    const int wave = tid >> 6, lane = tid & 63;
    const int row = lane & 15, g = lane >> 4;
    const int fcol = wave * 32 + row;

    const ushort* wp0 = wT + (size_t)fcol * 256 + g * 8;
    short8v bA[8], bB[8];
#pragma unroll
    for (int kk = 0; kk < 8; kk++) bA[kk] = *(const short8v*)&wp0[kk * 32];
#pragma unroll
    for (int kk = 0; kk < 8; kk++) bB[kk] = *(const short8v*)&wp0[16 * 256 + kk * 32];
    const float bv0 = bias[fcol], bv1 = bias[fcol + 16];

    const int sr = tid >> 4, part = tid & 15;
    const int fnode = tid >> 4, fb = (tid & 15) * 8;

    for (int t = 0; t < 5; t++) {
        const int nloc = (tile0 + t) * 16;
        {
            size_t rowoff = (size_t)(nloc + sr) * INF + part * 16;
#pragma unroll
            for (int ii = 0; ii < 4; ii++) {
                float4 v = *(const float4*)&x[rowoff + ii * 4];
                ushort4 h = {f2bf(v.x), f2bf(v.y), f2bf(v.z), f2bf(v.w)};
                *(ushort4*)&sx[sr][part * 16 + ii * 4] = h;
            }
        }
        __syncthreads();
        short8v a[8];
#pragma unroll
        for (int kk = 0; kk < 8; kk++) a[kk] = *(const short8v*)&sx[row][kk * 32 + g * 8];
        {
            f32x4 acc0 = {0.f, 0.f, 0.f, 0.f};
            f32x4 acc1 = {0.f, 0.f, 0.f, 0.f};
#pragma unroll
            for (int kk = 0; kk < 8; kk++) {
                acc0 = __builtin_amdgcn_mfma_f32_16x16x32_bf16(a[kk], bA[kk], acc0, 0, 0, 0);
                acc1 = __builtin_amdgcn_mfma_f32_16x16x32_bf16(a[kk], bB[kk], acc1, 0, 0, 0);
            }
#pragma unroll
            for (int q = 0; q < 4; q++) {
                so[g * 4 + q][fcol]      = f2bf(fmaxf(acc0[q] + bv0, 0.f));
                so[g * 4 + q][fcol + 16] = f2bf(fmaxf(acc1[q] + bv1, 0.f));
            }
        }
        __syncthreads();
        {
            ushort4 v0 = *(const ushort4*)&so[fnode][fb];
            ushort4 v1 = *(const ushort4*)&so[fnode][fb + 4];
            size_t gbase = (size_t)(typeBase + nloc + fnode) * 128 + fb;
            *(ushort4*)&x0b[gbase] = v0;
            *(ushort4*)&x0b[gbase + 4] = v1;
        }
    }
}

// ---------------------------------------------------------------------------
__global__ void scan1(const int* __restrict__ cnt, int* __restrict__ offs,
                      int* __restrict__ bsums, int n) {
    __shared__ int lds[256];
    const int t = threadIdx.x;
    const int base = blockIdx.x * 2048 + t * 8;
    int vals[8];
    int s = 0;
#pragma unroll
    for (int v = 0; v < 8; v++) {
        int idx = base + v;
        vals[v] = (idx < n) ? cnt[idx] : 0;
        s += vals[v];
    }
    lds[t] = s;
    __syncthreads();
    for (int off = 1; off < 256; off <<= 1) {
        int x = lds[t];
        int y = (t >= off) ? lds[t - off] : 0;
        __syncthreads();
        lds[t] = x + y;
        __syncthreads();
    }
    int run = (t > 0) ? lds[t - 1] : 0;
    if (t == 255) bsums[blockIdx.x] = lds[255];
#pragma unroll
    for (int v = 0; v < 8; v++) {
        int idx = base + v;
        if (idx < n) offs[idx] = run;
        run += vals[v];
    }
}

__global__ void scan2(const int* __restrict__ bsums, int* __restrict__ bsums2, int nb) {
    __shared__ int lds[256];
    const int t = threadIdx.x;
    lds[t] = (t < nb) ? bsums[t] : 0;
    __syncthreads();
    for (int off = 1; off < 256; off <<= 1) {
        int x = lds[t];
        int y = (t >= off) ? lds[t - off] : 0;
        __syncthreads();
        lds[t] = x + y;
        __syncthreads();
    }
    if (t < nb) bsums2[t] = (t > 0) ? lds[t - 1] : 0;
}

__global__ void scan3_desc(const int* __restrict__ offs, const int* __restrict__ bsums2,
                           const int* __restrict__ cnt, int2* __restrict__ desc, int n) {
    int i = blockIdx.x * blockDim.x + threadIdx.x;
    if (i < n) {
        int2 d = {offs[i] + bsums2[i >> 11], cnt[i]};
        desc[i] = d;
    }
}

// ---------------------------------------------------------------------------
// L0 dense GEMM (blocks 0..1249: both 64-col halves) + scatter (blocks 1250+),
// RANGE-SPLIT. Root contribution goes to bf16 seed0.
__launch_bounds__(256)
__global__ void gemm0_scatter(const ushort* __restrict__ xin,
                              const ushort* __restrict__ wbT_a, const ushort* __restrict__ wbT_b,
                              ushort* __restrict__ ytab, ushort* __restrict__ seed0,
                              const int* __restrict__ ei, const int* __restrict__ et,
                              const int* __restrict__ rank,
                              const int2* __restrict__ desc, int2* __restrict__ recs) {
    __shared__ ushort sx[32][136];
    __shared__ ushort so[32][328];
    __shared__ float sroot[32][68];
    const int tid = threadIdx.x;
    if (blockIdx.x >= 1250) {             // ---- scatter part ----
        int e = (blockIdx.x - 1250) * 256 + tid;
        if (e < NE) {
            int src = ei[e];
            int dst = ei[NE + e];
            int r = et[e];
            int2 d = desc[dst * NREL + r];
            int c = d.y;
            float sc = 1.f / (float)((c > 1) ? c : 1);
            int2 rec = {r * NN + src, __builtin_bit_cast(int, sc)};
            recs[d.x + rank[e]] = rec;
        }
        return;
    }
    // ---- gemm0 part ----
    const bool first = blockIdx.x < 625;
    const int tile0 = (first ? blockIdx.x : blockIdx.x - 625) * 5;
    const ushort* wbT = first ? wbT_a : wbT_b;
    const int outOff = first ? 0 : 64;
    const int wave = tid >> 6, lane = tid & 63;
    const int row = lane & 15, g = lane >> 4;
    const int wbase = wave * 96;

    const ushort* wp = wbT + (size_t)(wbase + row) * 128 + g * 8;
    short8v B[6][4];
#pragma unroll
    for (int t = 0; t < 6; t++)
#pragma unroll
        for (int kk = 0; kk < 4; kk++)
            B[t][kk] = *(const short8v*)&wp[t * 2048 + kk * 32];

    const int sr = tid >> 3, scl = (tid & 7) * 16;
    const int fnode = tid >> 3, fb = (tid & 7) * 8;

    for (int tt = 0; tt < 5; tt++) {
        const int n0 = (tile0 + tt) * 32;
        {
            const ushort* src = &xin[(size_t)(n0 + sr) * 128 + scl];
            *(short8v*)&sx[sr][scl] = *(const short8v*)&src[0];
            *(short8v*)&sx[sr][scl + 8] = *(const short8v*)&src[8];
        }
        __syncthreads();

        short8v a[2][4];
#pragma unroll
        for (int m = 0; m < 2; m++)
#pragma unroll
            for (int kk = 0; kk < 4; kk++)
                a[m][kk] = *(const short8v*)&sx[m * 16 + row][kk * 32 + g * 8];

#pragma unroll
        for (int t = 0; t < 6; t++) {
            f32x4 acc0 = {0.f, 0.f, 0.f, 0.f};
            f32x4 acc1 = {0.f, 0.f, 0.f, 0.f};
#pragma unroll
            for (int kk = 0; kk < 4; kk++) {
                acc0 = __builtin_amdgcn_mfma_f32_16x16x32_bf16(a[0][kk], B[t][kk], acc0, 0, 0, 0);
                acc1 = __builtin_amdgcn_mfma_f32_16x16x32_bf16(a[1][kk], B[t][kk], acc1, 0, 0, 0);
            }
            const int col = wbase + t * 16 + row;
            if (col < 320) {
#pragma unroll
                for (int q = 0; q < 4; q++) {
                    so[g * 4 + q][col] = f2bf(acc0[q]);
                    so[16 + g * 4 + q][col] = f2bf(acc1[q]);
                }
            } else {
                const int f = col - 320;
#pragma unroll
                for (int q = 0; q < 4; q++) {
                    sroot[g * 4 + q][f] = acc0[q];
                    sroot[16 + g * 4 + q][f] = acc1[q];
                }
            }
        }
        __syncthreads();

        {
#pragma unroll
            for (int r = 0; r < NREL; r++) {
                short8v v = *(const short8v*)&so[fnode][r * 64 + fb];
                *(short8v*)&ytab[(size_t)r * NN * 128 + (size_t)(n0 + fnode) * 128
                                 + outOff + fb] = v;
            }
            float4 r0 = *(const float4*)&sroot[fnode][fb];
            float4 r1 = *(const float4*)&sroot[fnode][fb + 4];
            ushort sb[8] = {f2bf(r0.x), f2bf(r0.y), f2bf(r0.z), f2bf(r0.w),
                            f2bf(r1.x), f2bf(r1.y), f2bf(r1.z), f2bf(r1.w)};
            *(short8v*)&seed0[(size_t)(n0 + fnode) * 128 + outOff + fb] =
                *(const short8v*)sb;
        }
    }
}

// ---------------------------------------------------------------------------
// L1 dense GEMM with FUSED PairNorm-0 on input (writes x_latent in place);
// root contribution goes to bf16 seed1.
__launch_bounds__(256)
__global__ void ytab_gemm1(float* __restrict__ h0x, const float* __restrict__ mu,
                           const ushort* __restrict__ wbT,
                           ushort* __restrict__ ytab, ushort* __restrict__ seed1) {
    __shared__ ushort sx[32][136];
    __shared__ ushort so[32][328];
    __shared__ float sroot[32][68];
    const int tid = threadIdx.x;
    const int tile0 = blockIdx.x * 5;
    const int wave = tid >> 6, lane = tid & 63;
    const int row = lane & 15, g = lane >> 4;
    const int wbase = wave * 96;

    const ushort* wp = wbT + (size_t)(wbase + row) * 128 + g * 8;
    short8v B[6][4];
#pragma unroll
    for (int t = 0; t < 6; t++)
#pragma unroll
        for (int kk = 0; kk < 4; kk++)
            B[t][kk] = *(const short8v*)&wp[t * 2048 + kk * 32];

    const int sr = tid >> 3, scl = (tid & 7) * 16;
    const int fnode = tid >> 3, fb = (tid & 7) * 8;

    float m[16];
#pragma unroll
    for (int i = 0; i < 16; i++) m[i] = mu[scl + i];
    const float s = mu[128];

    for (int tt = 0; tt < 5; tt++) {
        const int n0 = (tile0 + tt) * 32;
        {   // stage + normalize + write-back (in place)
            float* hp = &h0x[(size_t)(n0 + sr) * 128 + scl];
            float v[16];
#pragma unroll
            for (int i = 0; i < 4; i++) {
                float4 t4 = *(const float4*)&hp[i * 4];
                v[i * 4 + 0] = (t4.x - m[i * 4 + 0]) * s;
                v[i * 4 + 1] = (t4.y - m[i * 4 + 1]) * s;
                v[i * 4 + 2] = (t4.z - m[i * 4 + 2]) * s;
                v[i * 4 + 3] = (t4.w - m[i * 4 + 3]) * s;
            }
            ushort hb[16];
#pragma unroll
            for (int i = 0; i < 16; i++) hb[i] = f2bf(v[i]);
#pragma unroll
            for (int i = 0; i < 4; i++) {
                float4 t4 = {v[i * 4], v[i * 4 + 1], v[i * 4 + 2], v[i * 4 + 3]};
                *(float4*)&hp[i * 4] = t4;
            }
            *(short8v*)&sx[sr][scl] = *(const short8v*)&hb[0];
            *(short8v*)&sx[sr][scl + 8] = *(const short8v*)&hb[8];
        }
        __syncthreads();

        short8v a[2][4];
#pragma unroll
        for (int mi = 0; mi < 2; mi++)
#pragma unroll
            for (int kk = 0; kk < 4; kk++)
                a[mi][kk] = *(const short8v*)&sx[mi * 16 + row][kk * 32 + g * 8];

#pragma unroll
        for (int t = 0; t < 6; t++) {
            f32x4 acc0 = {0.f, 0.f, 0.f, 0.f};
            f32x4 acc1 = {0.f, 0.f, 0.f, 0.f};
#pragma unroll
            for (int kk = 0; kk < 4; kk++) {
                acc0 = __builtin_amdgcn_mfma_f32_16x16x32_bf16(a[0][kk], B[t][kk], acc0, 0, 0, 0);
                acc1 = __builtin_amdgcn_mfma_f32_16x16x32_bf16(a[1][kk], B[t][kk], acc1, 0, 0, 0);
            }
            const int col = wbase + t * 16 + row;
            if (col < 320) {
#pragma unroll
                for (int q = 0; q < 4; q++) {
                    so[g * 4 + q][col] = f2bf(acc0[q]);
                    so[16 + g * 4 + q][col] = f2bf(acc1[q]);
                }
            } else {
                const int f = col - 320;
#pragma unroll
                for (int q = 0; q < 4; q++) {
                    sroot[g * 4 + q][f] = acc0[q];
                    sroot[16 + g * 4 + q][f] = acc1[q];
                }
            }
        }
        __syncthreads();

        {
#pragma unroll
            for (int r = 0; r < NREL; r++) {
                short8v v = *(const short8v*)&so[fnode][r * 64 + fb];
                *(short8v*)&ytab[(size_t)r * NN * 64 + (size_t)(n0 + fnode) * 64 + fb] = v;
            }
            float4 r0 = *(const float4*)&sroot[fnode][fb];
            float4 r1 = *(const float4*)&sroot[fnode][fb + 4];
            ushort sb[8] = {f2bf(r0.x), f2bf(r0.y), f2bf(r0.z), f2bf(r0.w),
                            f2bf(r1.x), f2bf(r1.y), f2bf(r1.z), f2bf(r1.w)};
            *(short8v*)&seed1[(size_t)(n0 + fnode) * 64 + fb] = *(const short8v*)sb;
        }
    }
}

// ---------------------------------------------------------------------------
// Aggregation + FUSED PairNorm stats. Quarter-wave (16 lanes) per edge,
// wave-uniform trip count (shfl-safe). bf16 seed in, f32 h out.
template <int FW, bool RELU>
__launch_bounds__(256)
__global__ void agg_kernel(const ushort* __restrict__ ytab,
                           const ushort* __restrict__ seed,
                           const int2* __restrict__ recs,
                           const int2* __restrict__ desc,
                           float* __restrict__ hout,
                           float* __restrict__ csrep, float* __restrict__ ssrep) {
    constexpr int FPL = FW / 16;          // floats per lane (8 or 4)
    __shared__ float sred[4][16][FPL + 1];
    const int tid = threadIdx.x;
    const int wave = tid >> 6, lane = tid & 63;
    const int q = lane >> 4, fl = lane & 15;
    const int n0 = blockIdx.x * 16 + wave * 4;

    int start[4], total[4];
#pragma unroll
    for (int rep = 0; rep < 4; rep++) {
        const int s5 = (n0 + rep) * NREL;
        int2 d0 = desc[s5];
        int2 d4 = desc[s5 + 4];
        start[rep] = d0.x;
        total[rep] = d4.x + d4.y - d0.x;
    }
    float hpre[4][FPL];
#pragma unroll
    for (int rep = 0; rep < 4; rep++) {
        if (FW == 128) {
            uint4 sraw = *(const uint4*)&seed[(size_t)(n0 + rep) * FW + fl * 8];
            hpre[rep][0] = bflo(sraw.x); hpre[rep][1] = bfhi(sraw.x);
            hpre[rep][2] = bflo(sraw.y); hpre[rep][3] = bfhi(sraw.y);
            hpre[rep][4] = bflo(sraw.z); hpre[rep][5] = bfhi(sraw.z);
            hpre[rep][6] = bflo(sraw.w); hpre[rep][7] = bfhi(sraw.w);
        } else {
            uint2 sraw = *(const uint2*)&seed[(size_t)(n0 + rep) * FW + fl * 4];
            hpre[rep][0] = bflo(sraw.x); hpre[rep][1] = bfhi(sraw.x);
            hpre[rep][2] = bflo(sraw.y); hpre[rep][3] = bfhi(sraw.y);
        }
    }
    int2 rec[4];
#pragma unroll
    for (int rep = 0; rep < 4; rep++) rec[rep] = recs[start[rep] + lane];  // pad-safe

    float cs_loc[FPL];
#pragma unroll
    for (int k = 0; k < FPL; k++) cs_loc[k] = 0.f;
    float ss_loc = 0.f;

#pragma unroll
    for (int rep = 0; rep < 4; rep++) {
        float acc[FPL];
#pragma unroll
        for (int k = 0; k < FPL; k++) acc[k] = 0.f;
        const int lim = (total[rep] > 64) ? 64 : total[rep];   // wave-uniform
        const int iters = (lim + 3) >> 2;                      // wave-uniform
#pragma unroll 2
        for (int it = 0; it < iters; it++) {
            const int j4 = it * 4 + q;                         // <= 63 always
            int rwr = __shfl(rec[rep].x, j4);
            int scb = __shfl(rec[rep].y, j4);
            const bool ok = j4 < lim;
            const int rw = ok ? rwr : 0;
            const float sc = ok ? __builtin_bit_cast(float, scb) : 0.f;
            if (FW == 128) {
                uint4 raw = *(const uint4*)&ytab[(size_t)rw * FW + fl * 8];
                acc[0] += sc * bflo(raw.x); acc[1] += sc * bfhi(raw.x);
                acc[2] += sc * bflo(raw.y); acc[3] += sc * bfhi(raw.y);
                acc[4] += sc * bflo(raw.z); acc[5] += sc * bfhi(raw.z);
                acc[6] += sc * bflo(raw.w); acc[7] += sc * bfhi(raw.w);
            } else {
                uint2 raw = *(const uint2*)&ytab[(size_t)rw * FW + fl * 4];
                acc[0] += sc * bflo(raw.x); acc[1] += sc * bfhi(raw.x);
                acc[2] += sc * bflo(raw.y); acc[3] += sc * bfhi(raw.y);
            }
        }
        if (total[rep] > 64) {            // rare fallback (no shfl -> safe)
            for (int j = 64 + q; j < total[rep]; j += 4) {
                int2 r2 = recs[start[rep] + j];
                float sc = __builtin_bit_cast(float, r2.y);
                if (FW == 128) {
                    uint4 raw = *(const uint4*)&ytab[(size_t)r2.x * FW + fl * 8];
                    acc[0] += sc * bflo(raw.x); acc[1] += sc * bfhi(raw.x);
                    acc[2] += sc * bflo(raw.y); acc[3] += sc * bfhi(raw.y);
                    acc[4] += sc * bflo(raw.z); acc[5] += sc * bfhi(raw.z);
                    acc[6] += sc * bflo(raw.w); acc[7] += sc * bfhi(raw.w);
                } else {
                    uint2 raw = *(const uint2*)&ytab[(size_t)r2.x * FW + fl * 4];
                    acc[0] += sc * bflo(raw.x); acc[1] += sc * bfhi(raw.x);
                    acc[2] += sc * bflo(raw.y); acc[3] += sc * bfhi(raw.y);
                }
            }
        }
#pragma unroll
        for (int k = 0; k < FPL; k++) {
            acc[k] += __shfl_xor(acc[k], 32);
            acc[k] += __shfl_xor(acc[k], 16);
        }
        if (q == 0) {
            float o[FPL];
#pragma unroll
            for (int k = 0; k < FPL; k++) {
                o[k] = hpre[rep][k] + acc[k];
                if (RELU) o[k] = fmaxf(o[k], 0.f);
                cs_loc[k] += o[k];
                ss_loc += o[k] * o[k];
            }
            float* hp = &hout[(size_t)(n0 + rep) * FW + fl * FPL];
#pragma unroll
            for (int k = 0; k < FPL; k += 4)
                *(float4*)&hp[k] = *(float4*)&o[k];
        }
    }

    // block-level stats reduce -> replicated global accumulators
    if (q == 0) {
#pragma unroll
        for (int k = 0; k < FPL; k++) sred[wave][fl][k] = cs_loc[k];
        sred[wave][fl][FPL] = ss_loc;
    }
    __syncthreads();
    const int repl = blockIdx.x & 31;
    if (tid < FW) {
        int k = tid & (FPL - 1), f2 = tid / FPL;
        float sv = sred[0][f2][k] + sred[1][f2][k] + sred[2][f2][k] + sred[3][f2][k];
        atomicAdd(&csrep[repl * FW + f2 * FPL + k], sv);
    }
    if (tid < 16) {
        float ssv = sred[0][tid][FPL] + sred[1][tid][FPL]
                  + sred[2][tid][FPL] + sred[3][tid][FPL];
#pragma unroll
        for (int mof = 8; mof > 0; mof >>= 1) ssv += __shfl_xor(ssv, mof);
        if (tid == 0) atomicAdd(&ssrep[repl], ssv);
    }
}

// ---------------------------------------------------------------------------
template <int F>
__global__ void finalize_rep(const float* __restrict__ csrep,
                             const float* __restrict__ ssrep,
                             float* __restrict__ mu_inv) {
    __shared__ float sred[128];
    const int f = threadIdx.x;            // F threads
    float s = 0.f;
    for (int r = 0; r < 32; r++) s += csrep[r * F + f];
    float mu = s / (float)NN;
    mu_inv[f] = mu;
    sred[f] = mu * mu;
    __syncthreads();
    for (int h = F / 2; h > 0; h >>= 1) {
        if (f < h) sred[f] += sred[f + h];
        __syncthreads();
    }
    if (f == 0) {
        float ss = 0.f;
        for (int r = 0; r < 32; r++) ss += ssrep[r];
        float var = ss / (float)NN - sred[0];
        mu_inv[F] = rsqrtf(1e-5f + var);
    }
}

// final L1 normalize (in-place on d_out), float4-vectorized
template <int F>
__global__ void normalize_kernel(const float* __restrict__ x,
                                 const float* __restrict__ mu_inv,
                                 float* __restrict__ out, int total4) {
    int i = blockIdx.x * blockDim.x + threadIdx.x;
    if (i < total4) {
        int base = i * 4;
        int f = base & (F - 1);
        float4 v = *(const float4*)&x[base];
        float4 m = *(const float4*)&mu_inv[f];
        float s = mu_inv[F];
        float4 o = {(v.x - m.x) * s, (v.y - m.y) * s, (v.z - m.z) * s, (v.w - m.w) * s};
        *(float4*)&out[base] = o;
    }
}

// ---------------------------------------------------------------------------
extern "C" void kernel_launch(void* const* d_in, const int* in_sizes, int n_in,
                              void* d_out, int out_size, void* d_ws, size_t ws_size,
                              hipStream_t stream) {
    const float* xa    = (const float*)d_in[0];
    const float* xp    = (const float*)d_in[1];
    const int*   ei    = (const int*)d_in[2];
    const int*   et    = (const int*)d_in[3];
    const float* paw   = (const float*)d_in[4];
    const float* pab   = (const float*)d_in[5];
    const float* ppw   = (const float*)d_in[6];
    const float* ppb   = (const float*)d_in[7];
    const float* comp0 = (const float*)d_in[8];
    const float* basis0= (const float*)d_in[9];
    const float* root0 = (const float*)d_in[10];
    const float* comp1 = (const float*)d_in[11];
    const float* basis1= (const float*)d_in[12];
    const float* root1 = (const float*)d_in[13];
    float* out = (float*)d_out;

    char* ws = (char*)d_ws;
    size_t o = 0;
    auto alloc = [&](size_t b) { size_t p = o; o += (b + 255) & ~(size_t)255; return p; };
    ushort* x0b    = (ushort*)(ws + alloc((size_t)NN * HID * 2));        // 25.6 MB
    ushort* ytab   = (ushort*)(ws + alloc((size_t)NREL * NN * 128 * 2)); // 128 MB
    ushort* seed0  = (ushort*)(ws + alloc((size_t)NN * HID * 2));        // 25.6 MB
    ushort* seed1  = (ushort*)(ws + alloc((size_t)NN * OUTF * 2));       // 12.8 MB
    int2*   desc   = (int2*)(ws + alloc((size_t)NSEG * 8));              // 4 MB
    int2*   recs   = (int2*)(ws + alloc((size_t)(NE + 64) * 8));         // 8 MB
    int*    rank   = (int*)(ws + alloc((size_t)NE * 4));                 // 4 MB
    ushort* wbT0a  = (ushort*)(ws + alloc(384 * 128 * 2));
    ushort* wbT0b  = (ushort*)(ws + alloc(384 * 128 * 2));
    ushort* wbT1   = (ushort*)(ws + alloc(384 * 128 * 2));
    ushort* wpa    = (ushort*)(ws + alloc(128 * 256 * 2));
    ushort* wpp    = (ushort*)(ws + alloc(128 * 256 * 2));
    float*  statscr= (float*)(ws + alloc(6400 * 4));
    float*  mu0    = (float*)(ws + alloc(129 * 4));
    float*  mu1    = (float*)(ws + alloc(65 * 4));
    float* cs0rep = statscr;              // 32 x 128
    float* ss0rep = statscr + 4096;       // 32
    float* cs1rep = statscr + 4128;       // 32 x 64
    float* ss1rep = statscr + 6176;       // 32

    // index-build scratch aliased into ytab (cnt/offs/bsums dead after scan3_desc,
    // which completes before the first ytab write in gemm0_scatter)
    char* ybase = (char*)ytab;
    int* cnt    = (int*)(ybase);
    int* offs   = (int*)(ybase + (size_t)NSEG * 4);
    int* bsums  = (int*)(ybase + (size_t)NSEG * 8);
    int* bsums2 = (int*)(ybase + (size_t)NSEG * 8 + 4096);

    float* h0 = out + (size_t)NN * OUTF;   // [NN][128] f32 (x_latent slice)
    float* h1 = out;                       // [NN][64]  f32

    // prep (zeros + all weight builds), then proj FUSED (range-split) with hist
    prep_kernel<<<2812, 256, 0, stream>>>(comp0, basis0, root0, comp1, basis1, root1,
                                          paw, ppw, wbT0a, wbT0b, wbT1, wpa, wpp,
                                          cnt, statscr, (int*)(recs + NE));
    proj_hist<<<1250 + NEB, 256, 0, stream>>>(xa, xp, wpa, wpp, pab, ppb,
                                              x0b, ei, et, cnt, rank);

    // segment index
    const int nb = (NSEG + 2047) / 2048;
    scan1<<<nb, 256, 0, stream>>>(cnt, offs, bsums, NSEG);
    scan2<<<1, 256, 0, stream>>>(bsums, bsums2, nb);
    scan3_desc<<<(NSEG + 255) / 256, 256, 0, stream>>>(offs, bsums2, cnt, desc, NSEG);

    // layer 0: GEMM (both halves) FUSED (range-split) with scatter, agg+stats
    gemm0_scatter<<<1250 + NEB, 256, 0, stream>>>(x0b, wbT0a, wbT0b, ytab, seed0,
                                                  ei, et, rank, desc, recs);
    agg_kernel<128, true><<<NN / 16, 256, 0, stream>>>(ytab, seed0, recs, desc, h0,
                                                       cs0rep, ss0rep);
    finalize_rep<128><<<1, 128, 0, stream>>>(cs0rep, ss0rep, mu0);

    // layer 1: GEMM with fused PairNorm-0 (writes x_latent in place), agg+stats
    ytab_gemm1<<<625, 256, 0, stream>>>(h0, mu0, wbT1, ytab, seed1);
    agg_kernel<64, false><<<NN / 16, 256, 0, stream>>>(ytab, seed1, recs, desc, h1,
                                                       cs1rep, ss1rep);
    finalize_rep<64><<<1, 64, 0, stream>>>(cs1rep, ss1rep, mu1);
    normalize_kernel<OUTF><<<(NN * OUTF / 4 + 255) / 256, 256, 0, stream>>>(h1, mu1, out,
                                                                            NN * OUTF / 4);
}

// Round 15
// 341.932 us; speedup vs baseline: 1.3245x; 1.0013x over previous
//
#include <hip/hip_runtime.h>
#include <hip/hip_bf16.h>

constexpr int NPT    = 50000;
constexpr int NN     = 100000;
constexpr int NE     = 1000000;
constexpr int HID    = 128;
constexpr int OUTF   = 64;
constexpr int INF    = 256;
constexpr int NREL   = 5;
constexpr int NSEG   = NN * NREL;
constexpr int NEB    = (NE + 255) / 256;   // 3907 edge blocks
constexpr int NB1    = (NSEG + 2047) / 2048; // 245 scan1 blocks

typedef __attribute__((ext_vector_type(8))) short short8v;
typedef __attribute__((ext_vector_type(4))) float f32x4;

__device__ __forceinline__ ushort f2bf(float x) {
    uint u = __builtin_bit_cast(uint, x);
    uint r = (u + 0x7FFFu + ((u >> 16) & 1u)) >> 16;
    return (ushort)r;
}
__device__ __forceinline__ float bfhi(uint raw) {
    return __builtin_bit_cast(float, raw & 0xFFFF0000u);
}
__device__ __forceinline__ float bflo(uint raw) {
    return __builtin_bit_cast(float, raw << 16);
}

// ---------------------------------------------------------------------------
// fused prep: zero cnt/statscr/recs-pad + build all weight stacks in ONE launch
__device__ __forceinline__ void build_wbT_body(const float* __restrict__ comp,
                                               const float* __restrict__ basis,
                                               const float* __restrict__ root,
                                               ushort* __restrict__ wbT,
                                               int fout, int passOff, int idx) {
    int col = idx >> 7, k = idx & 127;
    float v;
    if (col < 320) {
        int r = col >> 6, f = (col & 63) + passOff;
        v = 0.f;
#pragma unroll
        for (int b = 0; b < 8; b++)
            v += comp[r * 8 + b] * basis[(b * 128 + k) * fout + f];
    } else {
        v = root[k * fout + (col - 320) + passOff];
    }
    wbT[col * 128 + k] = f2bf(v);
}

__global__ void prep_kernel(const float* __restrict__ comp0, const float* __restrict__ basis0,
                            const float* __restrict__ root0,
                            const float* __restrict__ comp1, const float* __restrict__ basis1,
                            const float* __restrict__ root1,
                            const float* __restrict__ paw, const float* __restrict__ ppw,
                            ushort* __restrict__ wbT0a, ushort* __restrict__ wbT0b,
                            ushort* __restrict__ wbT1,
                            ushort* __restrict__ wpa, ushort* __restrict__ wpp,
                            int* __restrict__ cnt, float* __restrict__ statscr,
                            int* __restrict__ recs_pad) {
    const int b = blockIdx.x, t = threadIdx.x;
    if (b < 1954) {                       // zero cnt[NSEG]
        int i = b * 256 + t;
        if (i < NSEG) cnt[i] = 0;
    } else if (b < 1979) {                // zero statscr[6400]
        statscr[(b - 1954) * 256 + t] = 0.f;
    } else if (b == 1979) {               // zero recs pad (64 int2)
        if (t < 128) recs_pad[t] = 0;
    } else if (b < 2172) {
        build_wbT_body(comp0, basis0, root0, wbT0a, HID, 0, (b - 1980) * 256 + t);
    } else if (b < 2364) {
        build_wbT_body(comp0, basis0, root0, wbT0b, HID, 64, (b - 2172) * 256 + t);
    } else if (b < 2556) {
        build_wbT_body(comp1, basis1, root1, wbT1, OUTF, 0, (b - 2364) * 256 + t);
    } else if (b < 2684) {                // wpa: w[256][128] -> wT[128][256]
        int i = (b - 2556) * 256 + t;
        wpa[(size_t)(i & 127) * 256 + (i >> 7)] = f2bf(paw[i]);
    } else {
        int i = (b - 2684) * 256 + t;
        wpp[(size_t)(i & 127) * 256 + (i >> 7)] = f2bf(ppw[i]);
    }
}

// ---------------------------------------------------------------------------
// proj (blocks 0..1249, B-stationary 5-tile loop) + hist (blocks 1250+),
// RANGE-SPLIT (temporal partitioning — interleave regresses 2x, R13).
__launch_bounds__(256)
__global__ void proj_hist(const float* __restrict__ xa, const float* __restrict__ xp,
                          const ushort* __restrict__ wTa, const ushort* __restrict__ wTp,
                          const float* __restrict__ ba, const float* __restrict__ bp,
                          ushort* __restrict__ x0b,
                          const int* __restrict__ ei, const int* __restrict__ et,
                          int* __restrict__ cnt, int* __restrict__ rank) {
    __shared__ ushort sx[16][264];
    __shared__ ushort so[16][132];
    const int tid = threadIdx.x;
    if (blockIdx.x >= 1250) {             // ---- hist part ----
        int e = (blockIdx.x - 1250) * 256 + tid;
        if (e < NE) {
            int seg = ei[NE + e] * NREL + et[e];
            rank[e] = atomicAdd(&cnt[seg], 1);
        }
        return;
    }
    // ---- proj part ----
    const bool author = blockIdx.x < 625;
    const int tile0 = (blockIdx.x - (author ? 0 : 625)) * 5;
    const float* x = author ? xa : xp;
    const ushort* wT = author ? wTa : wTp;
    const float* bias = author ? ba : bp;
    const int typeBase = author ? 0 : NPT;

    const int wave = tid >> 6, lane = tid & 63;
    const int row = lane & 15, g = lane >> 4;
    const int fcol = wave * 32 + row;

    const ushort* wp0 = wT + (size_t)fcol * 256 + g * 8;
    short8v bA[8], bB[8];
#pragma unroll
    for (int kk = 0; kk < 8; kk++) bA[kk] = *(const short8v*)&wp0[kk * 32];
#pragma unroll
    for (int kk = 0; kk < 8; kk++) bB[kk] = *(const short8v*)&wp0[16 * 256 + kk * 32];
    const float bv0 = bias[fcol], bv1 = bias[fcol + 16];

    const int sr = tid >> 4, part = tid & 15;
    const int fnode = tid >> 4, fb = (tid & 15) * 8;

    for (int t = 0; t < 5; t++) {
        const int nloc = (tile0 + t) * 16;
        {
            size_t rowoff = (size_t)(nloc + sr) * INF + part * 16;
#pragma unroll
            for (int ii = 0; ii < 4; ii++) {
                float4 v = *(const float4*)&x[rowoff + ii * 4];
                ushort4 h = {f2bf(v.x), f2bf(v.y), f2bf(v.z), f2bf(v.w)};
                *(ushort4*)&sx[sr][part * 16 + ii * 4] = h;
            }
        }
        __syncthreads();
        short8v a[8];
#pragma unroll
        for (int kk = 0; kk < 8; kk++) a[kk] = *(const short8v*)&sx[row][kk * 32 + g * 8];
        {
            f32x4 acc0 = {0.f, 0.f, 0.f, 0.f};
            f32x4 acc1 = {0.f, 0.f, 0.f, 0.f};
#pragma unroll
            for (int kk = 0; kk < 8; kk++) {
                acc0 = __builtin_amdgcn_mfma_f32_16x16x32_bf16(a[kk], bA[kk], acc0, 0, 0, 0);
                acc1 = __builtin_amdgcn_mfma_f32_16x16x32_bf16(a[kk], bB[kk], acc1, 0, 0, 0);
            }
#pragma unroll
            for (int q = 0; q < 4; q++) {
                so[g * 4 + q][fcol]      = f2bf(fmaxf(acc0[q] + bv0, 0.f));
                so[g * 4 + q][fcol + 16] = f2bf(fmaxf(acc1[q] + bv1, 0.f));
            }
        }
        __syncthreads();
        {
            ushort4 v0 = *(const ushort4*)&so[fnode][fb];
            ushort4 v1 = *(const ushort4*)&so[fnode][fb + 4];
            size_t gbase = (size_t)(typeBase + nloc + fnode) * 128 + fb;
            *(ushort4*)&x0b[gbase] = v0;
            *(ushort4*)&x0b[gbase + 4] = v1;
        }
    }
}

// ---------------------------------------------------------------------------
__global__ void scan1(const int* __restrict__ cnt, int* __restrict__ offs,
                      int* __restrict__ bsums, int n) {
    __shared__ int lds[256];
    const int t = threadIdx.x;
    const int base = blockIdx.x * 2048 + t * 8;
    int vals[8];
    int s = 0;
#pragma unroll
    for (int v = 0; v < 8; v++) {
        int idx = base + v;
        vals[v] = (idx < n) ? cnt[idx] : 0;
        s += vals[v];
    }
    lds[t] = s;
    __syncthreads();
    for (int off = 1; off < 256; off <<= 1) {
        int x = lds[t];
        int y = (t >= off) ? lds[t - off] : 0;
        __syncthreads();
        lds[t] = x + y;
        __syncthreads();
    }
    int run = (t > 0) ? lds[t - 1] : 0;
    if (t == 255) bsums[blockIdx.x] = lds[255];
#pragma unroll
    for (int v = 0; v < 8; v++) {
        int idx = base + v;
        if (idx < n) offs[idx] = run;
        run += vals[v];
    }
}

// scan2 folded in: each block LDS-scans the 245 block sums (redundant, cheap),
// then desc[i] = { global offset, count }.
__global__ void scan3_desc(const int* __restrict__ offs, const int* __restrict__ bsums,
                           const int* __restrict__ cnt, int2* __restrict__ desc,
                           int n, int nb) {
    __shared__ int sb[256];
    const int t = threadIdx.x;
    sb[t] = (t < nb) ? bsums[t] : 0;
    __syncthreads();
    for (int off = 1; off < 256; off <<= 1) {
        int x = sb[t];
        int y = (t >= off) ? sb[t - off] : 0;
        __syncthreads();
        sb[t] = x + y;          // inclusive scan
        __syncthreads();
    }
    int i = blockIdx.x * 256 + t;
    if (i < n) {
        int blk = i >> 11;
        int excl = (blk > 0) ? sb[blk - 1] : 0;
        int2 d = {offs[i] + excl, cnt[i]};
        desc[i] = d;
    }
}

// ---------------------------------------------------------------------------
// L0 dense GEMM (blocks 0..1249: both 64-col halves) + scatter (blocks 1250+),
// RANGE-SPLIT. Root contribution goes to bf16 seed0.
__launch_bounds__(256)
__global__ void gemm0_scatter(const ushort* __restrict__ xin,
                              const ushort* __restrict__ wbT_a, const ushort* __restrict__ wbT_b,
                              ushort* __restrict__ ytab, ushort* __restrict__ seed0,
                              const int* __restrict__ ei, const int* __restrict__ et,
                              const int* __restrict__ rank,
                              const int2* __restrict__ desc, int2* __restrict__ recs) {
    __shared__ ushort sx[32][136];
    __shared__ ushort so[32][328];
    __shared__ float sroot[32][68];
    const int tid = threadIdx.x;
    if (blockIdx.x >= 1250) {             // ---- scatter part ----
        int e = (blockIdx.x - 1250) * 256 + tid;
        if (e < NE) {
            int src = ei[e];
            int dst = ei[NE + e];
            int r = et[e];
            int2 d = desc[dst * NREL + r];
            int c = d.y;
            float sc = 1.f / (float)((c > 1) ? c : 1);
            int2 rec = {r * NN + src, __builtin_bit_cast(int, sc)};
            recs[d.x + rank[e]] = rec;
        }
        return;
    }
    // ---- gemm0 part ----
    const bool first = blockIdx.x < 625;
    const int tile0 = (first ? blockIdx.x : blockIdx.x - 625) * 5;
    const ushort* wbT = first ? wbT_a : wbT_b;
    const int outOff = first ? 0 : 64;
    const int wave = tid >> 6, lane = tid & 63;
    const int row = lane & 15, g = lane >> 4;
    const int wbase = wave * 96;

    const ushort* wp = wbT + (size_t)(wbase + row) * 128 + g * 8;
    short8v B[6][4];
#pragma unroll
    for (int t = 0; t < 6; t++)
#pragma unroll
        for (int kk = 0; kk < 4; kk++)
            B[t][kk] = *(const short8v*)&wp[t * 2048 + kk * 32];

    const int sr = tid >> 3, scl = (tid & 7) * 16;
    const int fnode = tid >> 3, fb = (tid & 7) * 8;

    for (int tt = 0; tt < 5; tt++) {
        const int n0 = (tile0 + tt) * 32;
        {
            const ushort* src = &xin[(size_t)(n0 + sr) * 128 + scl];
            *(short8v*)&sx[sr][scl] = *(const short8v*)&src[0];
            *(short8v*)&sx[sr][scl + 8] = *(const short8v*)&src[8];
        }
        __syncthreads();

        short8v a[2][4];
#pragma unroll
        for (int m = 0; m < 2; m++)
#pragma unroll
            for (int kk = 0; kk < 4; kk++)
                a[m][kk] = *(const short8v*)&sx[m * 16 + row][kk * 32 + g * 8];

#pragma unroll
        for (int t = 0; t < 6; t++) {
            f32x4 acc0 = {0.f, 0.f, 0.f, 0.f};
            f32x4 acc1 = {0.f, 0.f, 0.f, 0.f};
#pragma unroll
            for (int kk = 0; kk < 4; kk++) {
                acc0 = __builtin_amdgcn_mfma_f32_16x16x32_bf16(a[0][kk], B[t][kk], acc0, 0, 0, 0);
                acc1 = __builtin_amdgcn_mfma_f32_16x16x32_bf16(a[1][kk], B[t][kk], acc1, 0, 0, 0);
            }
            const int col = wbase + t * 16 + row;
            if (col < 320) {
#pragma unroll
                for (int q = 0; q < 4; q++) {
                    so[g * 4 + q][col] = f2bf(acc0[q]);
                    so[16 + g * 4 + q][col] = f2bf(acc1[q]);
                }
            } else {
                const int f = col - 320;
#pragma unroll
                for (int q = 0; q < 4; q++) {
                    sroot[g * 4 + q][f] = acc0[q];
                    sroot[16 + g * 4 + q][f] = acc1[q];
                }
            }
        }
        __syncthreads();

        {
#pragma unroll
            for (int r = 0; r < NREL; r++) {
                short8v v = *(const short8v*)&so[fnode][r * 64 + fb];
                *(short8v*)&ytab[(size_t)r * NN * 128 + (size_t)(n0 + fnode) * 128
                                 + outOff + fb] = v;
            }
            float4 r0 = *(const float4*)&sroot[fnode][fb];
            float4 r1 = *(const float4*)&sroot[fnode][fb + 4];
            ushort sb[8] = {f2bf(r0.x), f2bf(r0.y), f2bf(r0.z), f2bf(r0.w),
                            f2bf(r1.x), f2bf(r1.y), f2bf(r1.z), f2bf(r1.w)};
            *(short8v*)&seed0[(size_t)(n0 + fnode) * 128 + outOff + fb] =
                *(const short8v*)sb;
        }
    }
}

// ---------------------------------------------------------------------------
// L1 dense GEMM with FUSED PairNorm-0 on input (writes x_latent in place);
// root contribution goes to bf16 seed1.
__launch_bounds__(256)
__global__ void ytab_gemm1(float* __restrict__ h0x, const float* __restrict__ mu,
                           const ushort* __restrict__ wbT,
                           ushort* __restrict__ ytab, ushort* __restrict__ seed1) {
    __shared__ ushort sx[32][136];
    __shared__ ushort so[32][328];
    __shared__ float sroot[32][68];
    const int tid = threadIdx.x;
    const int tile0 = blockIdx.x * 5;
    const int wave = tid >> 6, lane = tid & 63;
    const int row = lane & 15, g = lane >> 4;
    const int wbase = wave * 96;

    const ushort* wp = wbT + (size_t)(wbase + row) * 128 + g * 8;
    short8v B[6][4];
#pragma unroll
    for (int t = 0; t < 6; t++)
#pragma unroll
        for (int kk = 0; kk < 4; kk++)
            B[t][kk] = *(const short8v*)&wp[t * 2048 + kk * 32];

    const int sr = tid >> 3, scl = (tid & 7) * 16;
    const int fnode = tid >> 3, fb = (tid & 7) * 8;

    float m[16];
#pragma unroll
    for (int i = 0; i < 16; i++) m[i] = mu[scl + i];
    const float s = mu[128];

    for (int tt = 0; tt < 5; tt++) {
        const int n0 = (tile0 + tt) * 32;
        {   // stage + normalize + write-back (in place)
            float* hp = &h0x[(size_t)(n0 + sr) * 128 + scl];
            float v[16];
#pragma unroll
            for (int i = 0; i < 4; i++) {
                float4 t4 = *(const float4*)&hp[i * 4];
                v[i * 4 + 0] = (t4.x - m[i * 4 + 0]) * s;
                v[i * 4 + 1] = (t4.y - m[i * 4 + 1]) * s;
                v[i * 4 + 2] = (t4.z - m[i * 4 + 2]) * s;
                v[i * 4 + 3] = (t4.w - m[i * 4 + 3]) * s;
            }
            ushort hb[16];
#pragma unroll
            for (int i = 0; i < 16; i++) hb[i] = f2bf(v[i]);
#pragma unroll
            for (int i = 0; i < 4; i++) {
                float4 t4 = {v[i * 4], v[i * 4 + 1], v[i * 4 + 2], v[i * 4 + 3]};
                *(float4*)&hp[i * 4] = t4;
            }
            *(short8v*)&sx[sr][scl] = *(const short8v*)&hb[0];
            *(short8v*)&sx[sr][scl + 8] = *(const short8v*)&hb[8];
        }
        __syncthreads();

        short8v a[2][4];
#pragma unroll
        for (int mi = 0; mi < 2; mi++)
#pragma unroll
            for (int kk = 0; kk < 4; kk++)
                a[mi][kk] = *(const short8v*)&sx[mi * 16 + row][kk * 32 + g * 8];

#pragma unroll
        for (int t = 0; t < 6; t++) {
            f32x4 acc0 = {0.f, 0.f, 0.f, 0.f};
            f32x4 acc1 = {0.f, 0.f, 0.f, 0.f};
#pragma unroll
            for (int kk = 0; kk < 4; kk++) {
                acc0 = __builtin_amdgcn_mfma_f32_16x16x32_bf16(a[0][kk], B[t][kk], acc0, 0, 0, 0);
                acc1 = __builtin_amdgcn_mfma_f32_16x16x32_bf16(a[1][kk], B[t][kk], acc1, 0, 0, 0);
            }
            const int col = wbase + t * 16 + row;
            if (col < 320) {
#pragma unroll
                for (int q = 0; q < 4; q++) {
                    so[g * 4 + q][col] = f2bf(acc0[q]);
                    so[16 + g * 4 + q][col] = f2bf(acc1[q]);
                }
            } else {
                const int f = col - 320;
#pragma unroll
                for (int q = 0; q < 4; q++) {
                    sroot[g * 4 + q][f] = acc0[q];
                    sroot[16 + g * 4 + q][f] = acc1[q];
                }
            }
        }
        __syncthreads();

        {
#pragma unroll
            for (int r = 0; r < NREL; r++) {
                short8v v = *(const short8v*)&so[fnode][r * 64 + fb];
                *(short8v*)&ytab[(size_t)r * NN * 64 + (size_t)(n0 + fnode) * 64 + fb] = v;
            }
            float4 r0 = *(const float4*)&sroot[fnode][fb];
            float4 r1 = *(const float4*)&sroot[fnode][fb + 4];
            ushort sb[8] = {f2bf(r0.x), f2bf(r0.y), f2bf(r0.z), f2bf(r0.w),
                            f2bf(r1.x), f2bf(r1.y), f2bf(r1.z), f2bf(r1.w)};
            *(short8v*)&seed1[(size_t)(n0 + fnode) * 64 + fb] = *(const short8v*)sb;
        }
    }
}

// ---------------------------------------------------------------------------
// Aggregation + FUSED PairNorm stats. Quarter-wave (16 lanes) per edge,
// wave-uniform trip count (shfl-safe). bf16 seed in, f32 h out.
// Rec staging uses a CLAMPED index (min(lane, total-1)): unconditional issue
// (R10 showed branch-predicated staging stalls) but out-of-range lanes
// duplicate one cache line instead of over-fetching 6x.
template <int FW, bool RELU>
__launch_bounds__(256)
__global__ void agg_kernel(const ushort* __restrict__ ytab,
                           const ushort* __restrict__ seed,
                           const int2* __restrict__ recs,
                           const int2* __restrict__ desc,
                           float* __restrict__ hout,
                           float* __restrict__ csrep, float* __restrict__ ssrep) {
    constexpr int FPL = FW / 16;          // floats per lane (8 or 4)
    __shared__ float sred[4][16][FPL + 1];
    const int tid = threadIdx.x;
    const int wave = tid >> 6, lane = tid & 63;
    const int q = lane >> 4, fl = lane & 15;
    const int n0 = blockIdx.x * 16 + wave * 4;

    int start[4], total[4];
#pragma unroll
    for (int rep = 0; rep < 4; rep++) {
        const int s5 = (n0 + rep) * NREL;
        int2 d0 = desc[s5];
        int2 d4 = desc[s5 + 4];
        start[rep] = d0.x;
        total[rep] = d4.x + d4.y - d0.x;
    }
    float hpre[4][FPL];
#pragma unroll
    for (int rep = 0; rep < 4; rep++) {
        if (FW == 128) {
            uint4 sraw = *(const uint4*)&seed[(size_t)(n0 + rep) * FW + fl * 8];
            hpre[rep][0] = bflo(sraw.x); hpre[rep][1] = bfhi(sraw.x);
            hpre[rep][2] = bflo(sraw.y); hpre[rep][3] = bfhi(sraw.y);
            hpre[rep][4] = bflo(sraw.z); hpre[rep][5] = bfhi(sraw.z);
            hpre[rep][6] = bflo(sraw.w); hpre[rep][7] = bfhi(sraw.w);
        } else {
            uint2 sraw = *(const uint2*)&seed[(size_t)(n0 + rep) * FW + fl * 4];
            hpre[rep][0] = bflo(sraw.x); hpre[rep][1] = bfhi(sraw.x);
            hpre[rep][2] = bflo(sraw.y); hpre[rep][3] = bfhi(sraw.y);
        }
    }
    int2 rec[4];
#pragma unroll
    for (int rep = 0; rep < 4; rep++) {
        int cl = total[rep] - 1;
        cl = (cl > 0) ? cl : 0;
        int li = (lane < cl) ? lane : cl;        // clamp: no over-fetch
        rec[rep] = recs[start[rep] + li];
    }

    float cs_loc[FPL];
#pragma unroll
    for (int k = 0; k < FPL; k++) cs_loc[k] = 0.f;
    float ss_loc = 0.f;

#pragma unroll
    for (int rep = 0; rep < 4; rep++) {
        float acc[FPL];
#pragma unroll
        for (int k = 0; k < FPL; k++) acc[k] = 0.f;
        const int lim = (total[rep] > 64) ? 64 : total[rep];   // wave-uniform
        const int iters = (lim + 3) >> 2;                      // wave-uniform
#pragma unroll 2
        for (int it = 0; it < iters; it++) {
            const int j4 = it * 4 + q;                         // <= 63 always
            int rwr = __shfl(rec[rep].x, j4);
            int scb = __shfl(rec[rep].y, j4);
            const bool ok = j4 < lim;
            const int rw = ok ? rwr : 0;
            const float sc = ok ? __builtin_bit_cast(float, scb) : 0.f;
            if (FW == 128) {
                uint4 raw = *(const uint4*)&ytab[(size_t)rw * FW + fl * 8];
                acc[0] += sc * bflo(raw.x); acc[1] += sc * bfhi(raw.x);
                acc[2] += sc * bflo(raw.y); acc[3] += sc * bfhi(raw.y);
                acc[4] += sc * bflo(raw.z); acc[5] += sc * bfhi(raw.z);
                acc[6] += sc * bflo(raw.w); acc[7] += sc * bfhi(raw.w);
            } else {
                uint2 raw = *(const uint2*)&ytab[(size_t)rw * FW + fl * 4];
                acc[0] += sc * bflo(raw.x); acc[1] += sc * bfhi(raw.x);
                acc[2] += sc * bflo(raw.y); acc[3] += sc * bfhi(raw.y);
            }
        }
        if (total[rep] > 64) {            // rare fallback (no shfl -> safe)
            for (int j = 64 + q; j < total[rep]; j += 4) {
                int2 r2 = recs[start[rep] + j];
                float sc = __builtin_bit_cast(float, r2.y);
                if (FW == 128) {
                    uint4 raw = *(const uint4*)&ytab[(size_t)r2.x * FW + fl * 8];
                    acc[0] += sc * bflo(raw.x); acc[1] += sc * bfhi(raw.x);
                    acc[2] += sc * bflo(raw.y); acc[3] += sc * bfhi(raw.y);
                    acc[4] += sc * bflo(raw.z); acc[5] += sc * bfhi(raw.z);
                    acc[6] += sc * bflo(raw.w); acc[7] += sc * bfhi(raw.w);
                } else {
                    uint2 raw = *(const uint2*)&ytab[(size_t)r2.x * FW + fl * 4];
                    acc[0] += sc * bflo(raw.x); acc[1] += sc * bfhi(raw.x);
                    acc[2] += sc * bflo(raw.y); acc[3] += sc * bfhi(raw.y);
                }
            }
        }
#pragma unroll
        for (int k = 0; k < FPL; k++) {
            acc[k] += __shfl_xor(acc[k], 32);
            acc[k] += __shfl_xor(acc[k], 16);
        }
        if (q == 0) {
            float o[FPL];
#pragma unroll
            for (int k = 0; k < FPL; k++) {
                o[k] = hpre[rep][k] + acc[k];
                if (RELU) o[k] = fmaxf(o[k], 0.f);
                cs_loc[k] += o[k];
                ss_loc += o[k] * o[k];
            }
            float* hp = &hout[(size_t)(n0 + rep) * FW + fl * FPL];
#pragma unroll
            for (int k = 0; k < FPL; k += 4)
                *(float4*)&hp[k] = *(float4*)&o[k];
        }
    }

    // block-level stats reduce -> replicated global accumulators
    if (q == 0) {
#pragma unroll
        for (int k = 0; k < FPL; k++) sred[wave][fl][k] = cs_loc[k];
        sred[wave][fl][FPL] = ss_loc;
    }
    __syncthreads();
    const int repl = blockIdx.x & 31;
    if (tid < FW) {
        int k = tid & (FPL - 1), f2 = tid / FPL;
        float sv = sred[0][f2][k] + sred[1][f2][k] + sred[2][f2][k] + sred[3][f2][k];
        atomicAdd(&csrep[repl * FW + f2 * FPL + k], sv);
    }
    if (tid < 16) {
        float ssv = sred[0][tid][FPL] + sred[1][tid][FPL]
                  + sred[2][tid][FPL] + sred[3][tid][FPL];
#pragma unroll
        for (int mof = 8; mof > 0; mof >>= 1) ssv += __shfl_xor(ssv, mof);
        if (tid == 0) atomicAdd(&ssrep[repl], ssv);
    }
}

// ---------------------------------------------------------------------------
template <int F>
__global__ void finalize_rep(const float* __restrict__ csrep,
                             const float* __restrict__ ssrep,
                             float* __restrict__ mu_inv) {
    __shared__ float sred[128];
    const int f = threadIdx.x;            // F threads
    float s = 0.f;
    for (int r = 0; r < 32; r++) s += csrep[r * F + f];
    float mu = s / (float)NN;
    mu_inv[f] = mu;
    sred[f] = mu * mu;
    __syncthreads();
    for (int h = F / 2; h > 0; h >>= 1) {
        if (f < h) sred[f] += sred[f + h];
        __syncthreads();
    }
    if (f == 0) {
        float ss = 0.f;
        for (int r = 0; r < 32; r++) ss += ssrep[r];
        float var = ss / (float)NN - sred[0];
        mu_inv[F] = rsqrtf(1e-5f + var);
    }
}

// final L1 normalize (in-place on d_out), float4-vectorized
template <int F>
__global__ void normalize_kernel(const float* __restrict__ x,
                                 const float* __restrict__ mu_inv,
                                 float* __restrict__ out, int total4) {
    int i = blockIdx.x * blockDim.x + threadIdx.x;
    if (i < total4) {
        int base = i * 4;
        int f = base & (F - 1);
        float4 v = *(const float4*)&x[base];
        float4 m = *(const float4*)&mu_inv[f];
        float s = mu_inv[F];
        float4 o = {(v.x - m.x) * s, (v.y - m.y) * s, (v.z - m.z) * s, (v.w - m.w) * s};
        *(float4*)&out[base] = o;
    }
}

// ---------------------------------------------------------------------------
extern "C" void kernel_launch(void* const* d_in, const int* in_sizes, int n_in,
                              void* d_out, int out_size, void* d_ws, size_t ws_size,
                              hipStream_t stream) {
    const float* xa    = (const float*)d_in[0];
    const float* xp    = (const float*)d_in[1];
    const int*   ei    = (const int*)d_in[2];
    const int*   et    = (const int*)d_in[3];
    const float* paw   = (const float*)d_in[4];
    const float* pab   = (const float*)d_in[5];
    const float* ppw   = (const float*)d_in[6];
    const float* ppb   = (const float*)d_in[7];
    const float* comp0 = (const float*)d_in[8];
    const float* basis0= (const float*)d_in[9];
    const float* root0 = (const float*)d_in[10];
    const float* comp1 = (const float*)d_in[11];
    const float* basis1= (const float*)d_in[12];
    const float* root1 = (const float*)d_in[13];
    float* out = (float*)d_out;

    char* ws = (char*)d_ws;
    size_t o = 0;
    auto alloc = [&](size_t b) { size_t p = o; o += (b + 255) & ~(size_t)255; return p; };
    ushort* x0b    = (ushort*)(ws + alloc((size_t)NN * HID * 2));        // 25.6 MB
    ushort* ytab   = (ushort*)(ws + alloc((size_t)NREL * NN * 128 * 2)); // 128 MB
    ushort* seed0  = (ushort*)(ws + alloc((size_t)NN * HID * 2));        // 25.6 MB
    ushort* seed1  = (ushort*)(ws + alloc((size_t)NN * OUTF * 2));       // 12.8 MB
    int2*   desc   = (int2*)(ws + alloc((size_t)NSEG * 8));              // 4 MB
    int2*   recs   = (int2*)(ws + alloc((size_t)(NE + 64) * 8));         // 8 MB
    int*    rank   = (int*)(ws + alloc((size_t)NE * 4));                 // 4 MB
    ushort* wbT0a  = (ushort*)(ws + alloc(384 * 128 * 2));
    ushort* wbT0b  = (ushort*)(ws + alloc(384 * 128 * 2));
    ushort* wbT1   = (ushort*)(ws + alloc(384 * 128 * 2));
    ushort* wpa    = (ushort*)(ws + alloc(128 * 256 * 2));
    ushort* wpp    = (ushort*)(ws + alloc(128 * 256 * 2));
    float*  statscr= (float*)(ws + alloc(6400 * 4));
    float*  mu0    = (float*)(ws + alloc(129 * 4));
    float*  mu1    = (float*)(ws + alloc(65 * 4));
    float* cs0rep = statscr;              // 32 x 128
    float* ss0rep = statscr + 4096;       // 32
    float* cs1rep = statscr + 4128;       // 32 x 64
    float* ss1rep = statscr + 6176;       // 32

    // index-build scratch aliased into ytab (cnt/offs/bsums dead after scan3_desc,
    // which completes before the first ytab write in gemm0_scatter)
    char* ybase = (char*)ytab;
    int* cnt    = (int*)(ybase);
    int* offs   = (int*)(ybase + (size_t)NSEG * 4);
    int* bsums  = (int*)(ybase + (size_t)NSEG * 8);

    float* h0 = out + (size_t)NN * OUTF;   // [NN][128] f32 (x_latent slice)
    float* h1 = out;                       // [NN][64]  f32

    // prep (zeros + all weight builds), then proj FUSED (range-split) with hist
    prep_kernel<<<2812, 256, 0, stream>>>(comp0, basis0, root0, comp1, basis1, root1,
                                          paw, ppw, wbT0a, wbT0b, wbT1, wpa, wpp,
                                          cnt, statscr, (int*)(recs + NE));
    proj_hist<<<1250 + NEB, 256, 0, stream>>>(xa, xp, wpa, wpp, pab, ppb,
                                              x0b, ei, et, cnt, rank);

    // segment index (scan2 folded into scan3_desc)
    scan1<<<NB1, 256, 0, stream>>>(cnt, offs, bsums, NSEG);
    scan3_desc<<<(NSEG + 255) / 256, 256, 0, stream>>>(offs, bsums, cnt, desc, NSEG, NB1);

    // layer 0: GEMM (both halves) FUSED (range-split) with scatter, agg+stats
    gemm0_scatter<<<1250 + NEB, 256, 0, stream>>>(x0b, wbT0a, wbT0b, ytab, seed0,
                                                  ei, et, rank, desc, recs);
    agg_kernel<128, true><<<NN / 16, 256, 0, stream>>>(ytab, seed0, recs, desc, h0,
                                                       cs0rep, ss0rep);
    finalize_rep<128><<<1, 128, 0, stream>>>(cs0rep, ss0rep, mu0);

    // layer 1: GEMM with fused PairNorm-0 (writes x_latent in place), agg+stats
    ytab_gemm1<<<625, 256, 0, stream>>>(h0, mu0, wbT1, ytab, seed1);
    agg_kernel<64, false><<<NN / 16, 256, 0, stream>>>(ytab, seed1, recs, desc, h1,
                                                       cs1rep, ss1rep);
    finalize_rep<64><<<1, 64, 0, stream>>>(cs1rep, ss1rep, mu1);
    normalize_kernel<OUTF><<<(NN * OUTF / 4 + 255) / 256, 256, 0, stream>>>(h1, mu1, out,
                                                                            NN * OUTF / 4);
}